// Round 6
// baseline (141.590 us; speedup 1.0000x reference)
//
#include <hip/hip_runtime.h>
#include <math.h>

// Tropical (max-plus) matmul: y[b,o] = max_i (x[b,i] + W[o,i])
// x: [512,1024] f32, W: [1024,1024] f32 (K-innermost), y: [512,1024] f32.
//
// Round-6: ZERO-LDS partial via scalar-unit broadcast.
//   Diagnosis r5: dependency-stall-bound on the LDS round-trip (VALUBusy 28%,
//   conflicts 0, all pipes 30-40%); LDS fragment traffic floor ~10us at 8x8.
//   Fix: pre-transpose x,W into k-pair-major (xP[kp][m]{k,k+1}, wP[kp][n]{..}),
//   then per wave (16 m x 64 n): W-pair per-lane coalesced dwordx2 (depth-4
//   register prefetch), x-pair WAVE-UNIFORM load -> s_load (SGPR-pair operand
//   of v_pk_add_f32), v_max3_f32 into acc. 32 VALU / 32 triples per k-pair,
//   no DS ops at all. Epilogue stores 256B-contiguous per instruction
//   (r5's interleaved stores inflated WRITE_SIZE 64->113 MB).
// Split-K: KS=16 -> 2048 blocks x 4 waves, acc=16 VGPR -> high occupancy.

#define MDIM 512
#define NDIM 1024
#define KDIM 1024
#define KP2  (KDIM / 2)   // 512 k-pairs
#define TMR  16           // m-rows per wave
#define DPF  4            // W k-pair prefetch depth

typedef float v2f __attribute__((ext_vector_type(2)));

// pair-transpose: in = [R][2C] floats viewed as [R][C] v2f; out = [C][R] v2f.
// out[c][r] = {in[r][2c], in[r][2c+1]}
__global__ __launch_bounds__(256)
void pair_transpose(const v2f* __restrict__ in, v2f* __restrict__ out,
                    int R, int C) {
    __shared__ v2f t[32][33];
    const int tx = threadIdx.x & 31, ty = threadIdx.x >> 5;   // 32x8
    const int c0 = blockIdx.x * 32, r0 = blockIdx.y * 32;
#pragma unroll
    for (int j = 0; j < 4; ++j)
        t[ty + 8 * j][tx] = in[(size_t)(r0 + ty + 8 * j) * C + c0 + tx];
    __syncthreads();
#pragma unroll
    for (int j = 0; j < 4; ++j)
        out[(size_t)(c0 + ty + 8 * j) * R + r0 + tx] = t[tx][ty + 8 * j];
}

// partial: one wave covers 16 m-rows x 64 n-cols over this slice's k-pairs.
__global__ __launch_bounds__(256, 4)
void tropical_partial(const v2f* __restrict__ xP,   // [KP2][MDIM]
                      const v2f* __restrict__ wP,   // [KP2][NDIM]
                      float* __restrict__ part, int KCP) {
    const int wid  = threadIdx.x >> 6;
    const int lane = threadIdx.x & 63;
    const int task = blockIdx.x * 4 + wid;          // 0..511 per slice
    const int mb = task >> 4, nb = task & 15;       // 32 m-blocks x 16 n-blocks
    const int m0 = mb * TMR, n0 = nb * 64;
    const int kp0 = blockIdx.y * KCP;

    float acc[TMR];
#pragma unroll
    for (int i = 0; i < TMR; ++i) acc[i] = -INFINITY;

    const v2f* wcol = wP + (size_t)kp0 * NDIM + n0 + lane;  // per-lane, coalesced
    const v2f* xrow = xP + (size_t)kp0 * MDIM + m0;         // wave-uniform

    v2f wbuf[DPF];
#pragma unroll
    for (int d = 0; d < DPF; ++d) wbuf[d] = wcol[(size_t)d * NDIM];

#pragma unroll 4
    for (int kp = 0; kp < KCP; ++kp) {
        const v2f w2 = wbuf[kp & (DPF - 1)];
        if (kp + DPF < KCP)
            wbuf[kp & (DPF - 1)] = wcol[(size_t)(kp + DPF) * NDIM];
        const v2f* xr = xrow + (size_t)kp * MDIM;   // uniform -> s_load
#pragma unroll
        for (int i = 0; i < TMR; ++i) {
            const v2f s = w2 + xr[i];                        // v_pk_add_f32
            acc[i] = fmaxf(fmaxf(acc[i], s.x), s.y);         // v_max3_f32
        }
    }

    // epilogue: per i, wave writes 64 contiguous floats (256 B) -- full lines
    float* dst = part + (size_t)blockIdx.y * (MDIM * NDIM);
#pragma unroll
    for (int i = 0; i < TMR; ++i)
        dst[(size_t)(m0 + i) * NDIM + n0 + lane] = acc[i];
}

__global__ __launch_bounds__(256)
void tropical_reduce(const float* __restrict__ ws, float* __restrict__ out, int KS) {
    const int i = blockIdx.x * 256 + threadIdx.x;    // float4 index (exact grid)
    const int stride = MDIM * NDIM / 4;
    const float4* w4 = (const float4*)ws;
    float4 m = w4[i];
#pragma unroll 4
    for (int s = 1; s < KS; ++s) {
        const float4 v = w4[(size_t)s * stride + i];
        m.x = fmaxf(m.x, v.x); m.y = fmaxf(m.y, v.y);
        m.z = fmaxf(m.z, v.z); m.w = fmaxf(m.w, v.w);
    }
    ((float4*)out)[i] = m;
}

// correctness-only fallback if workspace is too small (never hit in harness)
__global__ __launch_bounds__(256)
void tropical_naive(const float* __restrict__ x, const float* __restrict__ W,
                    float* __restrict__ out) {
    const int idx = blockIdx.x * 256 + threadIdx.x;
    const int b = idx >> 10, n = idx & 1023;
    const float4* xr = (const float4*)(x + (size_t)b * KDIM);
    const float4* wr = (const float4*)(W + (size_t)n * KDIM);
    float m = -INFINITY;
    for (int k = 0; k < KDIM / 4; ++k) {
        const float4 a = xr[k], w = wr[k];
        m = fmaxf(m, fmaxf(fmaxf(a.x + w.x, a.y + w.y),
                           fmaxf(a.z + w.z, a.w + w.w)));
    }
    out[idx] = m;
}

extern "C" void kernel_launch(void* const* d_in, const int* in_sizes, int n_in,
                              void* d_out, int out_size, void* d_ws, size_t ws_size,
                              hipStream_t stream) {
    const float* x = (const float*)d_in[0];
    const float* W = (const float*)d_in[1];
    float* out = (float*)d_out;

    const size_t xPsz  = (size_t)KP2 * MDIM * sizeof(v2f);   // 2 MB
    const size_t wPsz  = (size_t)KP2 * NDIM * sizeof(v2f);   // 4 MB
    const size_t slice = (size_t)MDIM * NDIM * sizeof(float); // 2 MB

    int KS = 16;
    while (KS > 1 && xPsz + wPsz + (size_t)KS * slice > ws_size) KS >>= 1;

    if (xPsz + wPsz + slice > ws_size) {
        tropical_naive<<<MDIM * NDIM / 256, 256, 0, stream>>>(x, W, out);
        return;
    }

    v2f*   xP   = (v2f*)d_ws;
    v2f*   wP   = (v2f*)((char*)d_ws + xPsz);
    float* part = (float*)((char*)d_ws + xPsz + wPsz);

    // x: [512][512] v2f -> xP [512][512];  W: [1024][512] v2f -> wP [512][1024]
    pair_transpose<<<dim3(KP2 / 32, MDIM / 32), 256, 0, stream>>>(
        (const v2f*)x, xP, MDIM, KP2);
    pair_transpose<<<dim3(KP2 / 32, NDIM / 32), 256, 0, stream>>>(
        (const v2f*)W, wP, NDIM, KP2);

    const int KCP = KP2 / KS;                      // k-pairs per slice
    tropical_partial<<<dim3(128, KS), 256, 0, stream>>>(xP, wP, part, KCP);

    tropical_reduce<<<MDIM * NDIM / 4 / 256, 256, 0, stream>>>(part, out, KS);
}

// Round 7
// 138.034 us; speedup vs baseline: 1.0258x; 1.0258x over previous
//
#include <hip/hip_runtime.h>
#include <math.h>

// Tropical (max-plus) matmul: y[b,o] = max_i (x[b,i] + W[o,i])
// x: [512,1024] f32, W: [1024,1024] f32 (K-innermost), y: [512,1024] f32.
//
// Round-7: register-resident W-chunk + scalar-broadcast x, zero LDS.
//   Diagnosis r6: x DID scalarize (SGPR=48) but per-kp lgkmcnt(0) drains
//   (SMEM is OOO -> only full drains legal) every 32 VALU killed it, plus
//   W re-loaded per kp. Fix: amortize ALL per-wave memory:
//   - wave = 32m x 64n x 32k chunk; lane holds w[n0+lane][16 pairs] in
//     32 VGPRs, loaded ONCE per wave (coalesced via pair-transposed wT);
//   - per m: 16 uniform x-pairs (s_load, SGPR-pair src of v_pk_add_f32,
//     x slice is 32 CONTIGUOUS floats -> no x transpose) + 32 VALU
//     (v_pk_add_f32 + v_max3_f32) + one 256B coalesced store;
//   - zero LDS, zero barriers, VGPR ~45 -> launch_bounds(256,8) ->
//     8 waves/SIMD (TLP covers the per-m-group smem drains).
// Split-K: 32 slices -> part (64 MB, L3-resident) -> 32-deep reduce.

#define MDIM 512
#define NDIM 1024
#define KDIM 1024
#define KP2  (KDIM / 2)     // 512 k-pairs
#define NSLICE 32           // K-chunks of 32 floats (16 pairs)
#define MB 32               // m-rows per wave
#define NBW 64              // n-cols per wave (= lanes)

typedef float v2f __attribute__((ext_vector_type(2)));

// pair-transpose: in = [R][2C] floats viewed as [R][C] v2f; out = [C][R] v2f.
// out[c][r] = {in[r][2c], in[r][2c+1]}   (verified in round 6, absmax 0)
__global__ __launch_bounds__(256)
void pair_transpose(const v2f* __restrict__ in, v2f* __restrict__ out,
                    int R, int C) {
    __shared__ v2f t[32][33];
    const int tx = threadIdx.x & 31, ty = threadIdx.x >> 5;   // 32x8
    const int c0 = blockIdx.x * 32, r0 = blockIdx.y * 32;
#pragma unroll
    for (int j = 0; j < 4; ++j)
        t[ty + 8 * j][tx] = in[(size_t)(r0 + ty + 8 * j) * C + c0 + tx];
    __syncthreads();
#pragma unroll
    for (int j = 0; j < 4; ++j)
        out[(size_t)(c0 + ty + 8 * j) * R + r0 + tx] = t[tx][ty + 8 * j];
}

// partial: one wave = 32 m x 64 n over one 32-k chunk.
__global__ __launch_bounds__(256, 8)
void tropical_partial(const float* __restrict__ x,   // [512][1024], original
                      const v2f*  __restrict__ wT,   // [KP2][NDIM] pair-major
                      float* __restrict__ part) {
    const int lane = threadIdx.x & 63;
    const int wid  = threadIdx.x >> 6;
    const int task = blockIdx.x * 4 + wid;           // 0..8191
    const int slice = task & 31;                     // same-block waves:
    const int nb    = (task >> 5) & 15;              //  consecutive slices,
    const int mb    = task >> 9;                     //  same (mb, nb)
    const int m0 = mb * MB, n0 = nb * NBW;
    const int kp0 = slice * 16;                      // 16 pairs per chunk

    // W-chunk: lane's 16 k-pairs, loaded once (coalesced: 512B per inst)
    v2f w[16];
    const v2f* wcol = wT + (size_t)kp0 * NDIM + n0 + lane;
#pragma unroll
    for (int p = 0; p < 16; ++p) w[p] = wcol[(size_t)p * NDIM];

    const float* xg = x + (size_t)m0 * KDIM + slice * 32;   // uniform rows
    float* dst = part + (size_t)slice * (MDIM * NDIM)
                      + (size_t)m0 * NDIM + n0 + lane;

#pragma unroll 4
    for (int m = 0; m < MB; ++m) {
        const v2f* xp = (const v2f*)(xg + (size_t)m * KDIM);  // uniform -> s_load
        float a = -INFINITY;
#pragma unroll
        for (int p = 0; p < 16; ++p) {
            const v2f s = w[p] + xp[p];                   // v_pk_add_f32 (sgpr src)
            a = fmaxf(fmaxf(a, s.x), s.y);                // v_max3_f32
        }
        dst[(size_t)m * NDIM] = a;                        // 256B/wave, full lines
    }
}

__global__ __launch_bounds__(256)
void tropical_reduce(const float* __restrict__ ws, float* __restrict__ out,
                     int KS) {
    const int i = blockIdx.x * 256 + threadIdx.x;    // float4 index (exact grid)
    const int stride = MDIM * NDIM / 4;
    const float4* w4 = (const float4*)ws;
    float4 m = w4[i];
#pragma unroll 8
    for (int s = 1; s < KS; ++s) {
        const float4 v = w4[(size_t)s * stride + i];
        m.x = fmaxf(m.x, v.x); m.y = fmaxf(m.y, v.y);
        m.z = fmaxf(m.z, v.z); m.w = fmaxf(m.w, v.w);
    }
    ((float4*)out)[i] = m;
}

// correctness-only fallback if workspace is too small
__global__ __launch_bounds__(256)
void tropical_naive(const float* __restrict__ x, const float* __restrict__ W,
                    float* __restrict__ out) {
    const int idx = blockIdx.x * 256 + threadIdx.x;
    const int b = idx >> 10, n = idx & 1023;
    const float4* xr = (const float4*)(x + (size_t)b * KDIM);
    const float4* wr = (const float4*)(W + (size_t)n * KDIM);
    float m = -INFINITY;
    for (int k = 0; k < KDIM / 4; ++k) {
        const float4 a = xr[k], w = wr[k];
        m = fmaxf(m, fmaxf(fmaxf(a.x + w.x, a.y + w.y),
                           fmaxf(a.z + w.z, a.w + w.w)));
    }
    out[idx] = m;
}

extern "C" void kernel_launch(void* const* d_in, const int* in_sizes, int n_in,
                              void* d_out, int out_size, void* d_ws, size_t ws_size,
                              hipStream_t stream) {
    const float* x = (const float*)d_in[0];
    const float* W = (const float*)d_in[1];
    float* out = (float*)d_out;

    const size_t wTsz  = (size_t)KP2 * NDIM * sizeof(v2f);    // 4 MB
    const size_t slice = (size_t)MDIM * NDIM * sizeof(float); // 2 MB
    const size_t need  = wTsz + (size_t)NSLICE * slice;       // 68 MB

    if (need > ws_size) {
        tropical_naive<<<MDIM * NDIM / 256, 256, 0, stream>>>(x, W, out);
        return;
    }

    v2f*   wT   = (v2f*)d_ws;
    float* part = (float*)((char*)d_ws + wTsz);

    // W: [1024][512] v2f -> wT [512][1024]
    pair_transpose<<<dim3(KP2 / 32, NDIM / 32), 256, 0, stream>>>(
        (const v2f*)W, wT, NDIM, KP2);

    // 8192 wave-tasks = 2048 blocks x 4 waves; 8 blocks/CU, 32 waves/CU
    tropical_partial<<<2048, 256, 0, stream>>>(x, wT, part);

    tropical_reduce<<<MDIM * NDIM / 4 / 256, 256, 0, stream>>>(part, out, NSLICE);
}